// Round 3
// baseline (291.823 us; speedup 1.0000x reference)
//
#include <hip/hip_runtime.h>
#include <math.h>

#define DIN 512
#define DOUT 256
#define NEG_SLOPE 0.01f
#define GBM 256   // rows per block
#define GBN 64    // cols per block

typedef __attribute__((ext_vector_type(8))) short bf16x8;
typedef __attribute__((ext_vector_type(4))) float f32x4;
typedef __attribute__((ext_vector_type(4))) unsigned int u32x4;

__device__ __forceinline__ unsigned short f2bf(float f) {
    unsigned int u = __float_as_uint(f);
    unsigned int r = (u + 0x7FFFu + ((u >> 16) & 1u)) >> 16;
    return (unsigned short)r;
}
__device__ __forceinline__ float bf2f(unsigned short u) {
    return __uint_as_float(((unsigned int)u) << 16);
}
__device__ __forceinline__ unsigned int cvtpk(float lo, float hi) {
    unsigned int r;
    asm("v_cvt_pk_bf16_f32 %0, %1, %2" : "=v"(r) : "v"(lo), "v"(hi));
    return r;
}
__device__ __forceinline__ void gload16(const void* g, void* l) {
    __builtin_amdgcn_global_load_lds(
        (const __attribute__((address_space(1))) void*)g,
        (__attribute__((address_space(3))) void*)l, 16, 0, 0);
}

// ---------------- prep: Wt = bf16(W^T)  [DOUT][DIN], zero deg/s_src/s_dst ------------
__global__ void prep(const float* __restrict__ W, unsigned short* __restrict__ Wt,
                     int* __restrict__ deg, float* __restrict__ s_src,
                     float* __restrict__ s_dst, int N) {
    int t = blockIdx.x * blockDim.x + threadIdx.x;
    if (t < DIN * DOUT) {
        int k = t & (DIN - 1);
        int c = t >> 9;
        Wt[t] = f2bf(W[(size_t)k * DOUT + c]);  // coalesced write, L2-cached strided read
    }
    if (t < N) { deg[t] = 0; s_src[t] = 0.f; s_dst[t] = 0.f; }
}

// ---------------- GEMM: hb = bf16( x @ W ), fused s_src/s_dst partial dots ----------
// 512 threads = 8 waves; each wave: 32 rows x 64 cols. B slab (64 cols, full K) resident
// in LDS (XOR-swizzled via pre-swizzled global source). NO barriers in the K-loop.
__global__ __launch_bounds__(512) void gemm_k(const float* __restrict__ x,
                                              const unsigned short* __restrict__ Wt,
                                              unsigned short* __restrict__ hb,
                                              const float* __restrict__ av,
                                              float* __restrict__ s_src,
                                              float* __restrict__ s_dst, int M) {
    __shared__ unsigned char Bs[65536];  // 64 cols x 512 k x bf16, 16B-slot swizzled
    const int t = threadIdx.x;
    const int lane = t & 63;
    const int wv = t >> 6;      // 0..7
    const int m0 = blockIdx.x * GBM;
    const int n0 = blockIdx.y * GBN;

    // stage B once: wave wv stages cols wv*8 .. wv*8+7 (1KB each; lane l -> slot l)
#pragma unroll
    for (int it = 0; it < 8; ++it) {
        int c = wv * 8 + it;
        const unsigned short* src = Wt + (size_t)(n0 + c) * DIN + ((lane ^ (c & 7)) * 8);
        gload16(src, Bs + c * 1024);
    }

    // per-lane a-vector entries for the fused score dots
    float as_[4], ad_[4];
#pragma unroll
    for (int cf = 0; cf < 4; ++cf) {
        int col = n0 + cf * 16 + (lane & 15);
        as_[cf] = av[col];
        ad_[cf] = av[DOUT + col];
    }

    f32x4 acc[2][4] = {};
    const int g = lane >> 4;
    int row0 = m0 + wv * 32 + (lane & 15);
    int r0 = min(row0, M - 1);
    int r1 = min(row0 + 16, M - 1);
    const float* pA0 = x + (size_t)r0 * DIN + g * 8;
    const float* pA1 = x + (size_t)r1 * DIN + g * 8;

    __syncthreads();  // B resident; the only barrier

#pragma unroll 4
    for (int ks = 0; ks < DIN / 32; ++ks) {
        bf16x8 afr[2];
        {
            f32x4 v0 = *(const f32x4*)(pA0 + ks * 32);
            f32x4 v1 = *(const f32x4*)(pA0 + ks * 32 + 4);
            u32x4 p;
            p.x = cvtpk(v0.x, v0.y); p.y = cvtpk(v0.z, v0.w);
            p.z = cvtpk(v1.x, v1.y); p.w = cvtpk(v1.z, v1.w);
            afr[0] = *(bf16x8*)&p;
            f32x4 w0 = *(const f32x4*)(pA1 + ks * 32);
            f32x4 w1 = *(const f32x4*)(pA1 + ks * 32 + 4);
            u32x4 q;
            q.x = cvtpk(w0.x, w0.y); q.y = cvtpk(w0.z, w0.w);
            q.z = cvtpk(w1.x, w1.y); q.w = cvtpk(w1.z, w1.w);
            afr[1] = *(bf16x8*)&q;
        }
#pragma unroll
        for (int cf = 0; cf < 4; ++cf) {
            int col = cf * 16 + (lane & 15);
            bf16x8 bfr = *(const bf16x8*)(Bs + col * 1024 + (((ks * 4 + g) ^ (col & 7)) << 4));
            acc[0][cf] = __builtin_amdgcn_mfma_f32_16x16x32_bf16(afr[0], bfr, acc[0][cf], 0, 0, 0);
            acc[1][cf] = __builtin_amdgcn_mfma_f32_16x16x32_bf16(afr[1], bfr, acc[1][cf], 0, 0, 0);
        }
    }

    // epilogue: store hb + fused partial score dots (16-lane reduce + atomic per row)
#pragma unroll
    for (int rf = 0; rf < 2; ++rf) {
#pragma unroll
        for (int j = 0; j < 4; ++j) {
            int row = m0 + wv * 32 + rf * 16 + g * 4 + j;
            float ps = 0.f, pd = 0.f;
#pragma unroll
            for (int cf = 0; cf < 4; ++cf) {
                float v = acc[rf][cf][j];
                ps += v * as_[cf];
                pd += v * ad_[cf];
            }
#pragma unroll
            for (int off = 1; off < 16; off <<= 1) {
                ps += __shfl_xor(ps, off);
                pd += __shfl_xor(pd, off);
            }
            if (row < M) {
#pragma unroll
                for (int cf = 0; cf < 4; ++cf)
                    hb[(size_t)row * DOUT + n0 + cf * 16 + (lane & 15)] = f2bf(acc[rf][cf][j]);
                if ((lane & 15) == 0) {
                    atomicAdd(&s_src[row], ps);
                    atomicAdd(&s_dst[row], pd);
                }
            }
        }
    }
}

// ---------------- degree histogram ----------------
__global__ void hist_k(const int* __restrict__ src, int* __restrict__ deg, int E) {
    int i = blockIdx.x * blockDim.x + threadIdx.x;
    if (i < E) atomicAdd(&deg[src[i]], 1);
}

// ---------------- single-block exclusive scan -> rowptr, cursor ----------------
__global__ __launch_bounds__(1024) void scan_all(const int* __restrict__ deg,
                                                 int* __restrict__ rowptr,
                                                 int* __restrict__ cursor, int N, int E) {
    __shared__ int wsum[16];
    int t = threadIdx.x;
    const int C = (N + 1023) >> 10;
    int base = t * C;
    int s = 0;
    for (int i = 0; i < C; ++i) {
        int idx = base + i;
        if (idx < N) s += deg[idx];
    }
    int lane = t & 63, wid = t >> 6;
    int xx = s;
#pragma unroll
    for (int off = 1; off < 64; off <<= 1) {
        int y = __shfl_up(xx, off);
        if (lane >= off) xx += y;
    }
    if (lane == 63) wsum[wid] = xx;
    __syncthreads();
    int add = 0;
    for (int w = 0; w < wid; ++w) add += wsum[w];
    int run = add + xx - s;
    for (int i = 0; i < C; ++i) {
        int idx = base + i;
        if (idx < N) {
            rowptr[idx] = run;
            cursor[idx] = run;
            run += deg[idx];
        }
    }
    if (t == 0) rowptr[N] = E;
}

// ---------------- edge scoring + CSR scatter (packed pair) ----------------
__global__ void edge_k(const int* __restrict__ src, const int* __restrict__ dst,
                       const float* __restrict__ s_src, const float* __restrict__ s_dst,
                       int* __restrict__ cursor, int2* __restrict__ csr, int E) {
    int i = blockIdx.x * blockDim.x + threadIdx.x;
    if (i >= E) return;
    int s = src[i], d = dst[i];
    float sc = s_src[s] + s_dst[d];
    float lrv = sc > 0.f ? sc : NEG_SLOPE * sc;
    float ev = __expf(-lrv);
    int pos = atomicAdd(&cursor[s], 1);
    csr[pos] = make_int2(d, __float_as_int(ev));
}

// ---------------- per-row gather SpMM (bf16 h) + div + ELU ----------------
__global__ __launch_bounds__(256) void gather_k(const unsigned short* __restrict__ hb,
                                                const int* __restrict__ rowptr,
                                                const int2* __restrict__ csr,
                                                float* __restrict__ out, int N) {
    int gt = blockIdx.x * blockDim.x + threadIdx.x;
    int w = gt >> 6;
    int lane = threadIdx.x & 63;
    if (w >= N) return;
    int s0 = rowptr[w], s1 = rowptr[w + 1];
    float a0 = 0.f, a1 = 0.f, a2 = 0.f, a3 = 0.f, rs = 0.f;
    for (int base = s0; base < s1; base += 64) {
        int cnt = min(64, s1 - base);
        int dv = 0; float ev = 0.f;
        if (lane < cnt) {
            int2 p = csr[base + lane];
            dv = p.x; ev = __int_as_float(p.y);
        }
        int jj = 0;
        for (; jj + 4 <= cnt; jj += 4) {
            int d0 = __shfl(dv, jj), d1 = __shfl(dv, jj + 1), d2 = __shfl(dv, jj + 2), d3 = __shfl(dv, jj + 3);
            float e0 = __shfl(ev, jj), e1 = __shfl(ev, jj + 1), e2 = __shfl(ev, jj + 2), e3 = __shfl(ev, jj + 3);
            ushort4 h0 = *(const ushort4*)(hb + (size_t)d0 * DOUT + lane * 4);
            ushort4 h1 = *(const ushort4*)(hb + (size_t)d1 * DOUT + lane * 4);
            ushort4 h2 = *(const ushort4*)(hb + (size_t)d2 * DOUT + lane * 4);
            ushort4 h3 = *(const ushort4*)(hb + (size_t)d3 * DOUT + lane * 4);
            a0 += e0 * bf2f(h0.x) + e1 * bf2f(h1.x) + e2 * bf2f(h2.x) + e3 * bf2f(h3.x);
            a1 += e0 * bf2f(h0.y) + e1 * bf2f(h1.y) + e2 * bf2f(h2.y) + e3 * bf2f(h3.y);
            a2 += e0 * bf2f(h0.z) + e1 * bf2f(h1.z) + e2 * bf2f(h2.z) + e3 * bf2f(h3.z);
            a3 += e0 * bf2f(h0.w) + e1 * bf2f(h1.w) + e2 * bf2f(h2.w) + e3 * bf2f(h3.w);
            rs += e0 + e1 + e2 + e3;
        }
        for (; jj < cnt; ++jj) {
            int d0 = __shfl(dv, jj);
            float e0 = __shfl(ev, jj);
            ushort4 h0 = *(const ushort4*)(hb + (size_t)d0 * DOUT + lane * 4);
            a0 += e0 * bf2f(h0.x);
            a1 += e0 * bf2f(h0.y);
            a2 += e0 * bf2f(h0.z);
            a3 += e0 * bf2f(h0.w);
            rs += e0;
        }
    }
    float inv = 1.f / rs;
    float4 v;
    v.x = a0 * inv; v.y = a1 * inv; v.z = a2 * inv; v.w = a3 * inv;
    v.x = v.x > 0.f ? v.x : __expf(v.x) - 1.f;
    v.y = v.y > 0.f ? v.y : __expf(v.y) - 1.f;
    v.z = v.z > 0.f ? v.z : __expf(v.z) - 1.f;
    v.w = v.w > 0.f ? v.w : __expf(v.w) - 1.f;
    *(float4*)(out + (size_t)w * DOUT + lane * 4) = v;
}

extern "C" void kernel_launch(void* const* d_in, const int* in_sizes, int n_in,
                              void* d_out, int out_size, void* d_ws, size_t ws_size,
                              hipStream_t stream) {
    const float* x = (const float*)d_in[0];
    const float* W = (const float*)d_in[1];
    const float* a = (const float*)d_in[2];
    const int* edge_src = (const int*)d_in[3];
    const int* edge_dst = (const int*)d_in[4];

    const int N = in_sizes[0] / DIN;
    const int E = in_sizes[3];

    char* ws = (char*)d_ws;
    size_t off = 0;
    auto alloc = [&](size_t bytes) {
        void* p = ws + off;
        off += (bytes + 15) & ~(size_t)15;
        return p;
    };
    unsigned short* hb = (unsigned short*)alloc((size_t)N * DOUT * 2);
    unsigned short* Wt = (unsigned short*)alloc((size_t)DIN * DOUT * 2);
    int* rowptr = (int*)alloc((size_t)(N + 1) * 4);
    int* deg = (int*)alloc((size_t)N * 4);
    int* cursor = (int*)alloc((size_t)N * 4);
    float* s_src = (float*)alloc((size_t)N * 4);
    float* s_dst = (float*)alloc((size_t)N * 4);
    int2* csr = (int2*)alloc((size_t)E * 8);
    (void)ws_size;

    float* out = (float*)d_out;

    prep<<<(DIN * DOUT + 255) / 256, 256, 0, stream>>>(W, Wt, deg, s_src, s_dst, N);
    dim3 ggrid((N + GBM - 1) / GBM, DOUT / GBN);
    gemm_k<<<ggrid, 512, 0, stream>>>(x, Wt, hb, a, s_src, s_dst, N);
    hist_k<<<(E + 255) / 256, 256, 0, stream>>>(edge_src, deg, E);
    scan_all<<<1, 1024, 0, stream>>>(deg, rowptr, cursor, N, E);
    edge_k<<<(E + 255) / 256, 256, 0, stream>>>(edge_src, edge_dst, s_src, s_dst,
                                                cursor, csr, E);
    gather_k<<<(N + 3) / 4, 256, 0, stream>>>(hb, rowptr, csr, out, N);
}

// Round 4
// 178.980 us; speedup vs baseline: 1.6305x; 1.6305x over previous
//
#include <hip/hip_runtime.h>
#include <math.h>

#define DIN 512
#define DOUT 256
#define NEG_SLOPE 0.01f
#define GBM 256   // rows per block
#define GBN 64    // cols per block

typedef __attribute__((ext_vector_type(8))) short bf16x8;
typedef __attribute__((ext_vector_type(4))) float f32x4;
typedef __attribute__((ext_vector_type(4))) unsigned int u32x4;

__device__ __forceinline__ unsigned short f2bf(float f) {
    unsigned int u = __float_as_uint(f);
    unsigned int r = (u + 0x7FFFu + ((u >> 16) & 1u)) >> 16;
    return (unsigned short)r;
}
__device__ __forceinline__ float bf2f(unsigned short u) {
    return __uint_as_float(((unsigned int)u) << 16);
}
__device__ __forceinline__ unsigned int cvtpk(float lo, float hi) {
    unsigned int r;
    asm("v_cvt_pk_bf16_f32 %0, %1, %2" : "=v"(r) : "v"(lo), "v"(hi));
    return r;
}
__device__ __forceinline__ void gload16(const void* g, void* l) {
    __builtin_amdgcn_global_load_lds(
        (const __attribute__((address_space(1))) void*)g,
        (__attribute__((address_space(3))) void*)l, 16, 0, 0);
}

// ---------------- prep: Wt = bf16(W^T)  [DOUT][DIN], zero deg/s_src/s_dst ------------
__global__ void prep(const float* __restrict__ W, unsigned short* __restrict__ Wt,
                     int* __restrict__ deg, float* __restrict__ s_src,
                     float* __restrict__ s_dst, int N) {
    int t = blockIdx.x * blockDim.x + threadIdx.x;
    if (t < DIN * DOUT) {
        int k = t & (DIN - 1);
        int c = t >> 9;
        Wt[t] = f2bf(W[(size_t)k * DOUT + c]);  // coalesced write, L2-cached strided read
    }
    if (t < N) { deg[t] = 0; s_src[t] = 0.f; s_dst[t] = 0.f; }
}

// ---------------- GEMM: hb = bf16( x @ W ), fused s_src/s_dst partial dots ----------
// 512 threads = 8 waves; each wave: 32 rows x 64 cols. B slab (64 cols, full K) resident
// in LDS (XOR-swizzled via pre-swizzled global source). NO barriers in the K-loop.
__global__ __launch_bounds__(512) void gemm_k(const float* __restrict__ x,
                                              const unsigned short* __restrict__ Wt,
                                              unsigned short* __restrict__ hb,
                                              const float* __restrict__ av,
                                              float* __restrict__ s_src,
                                              float* __restrict__ s_dst, int M) {
    __shared__ unsigned char Bs[65536];  // 64 cols x 512 k x bf16, 16B-slot swizzled
    const int t = threadIdx.x;
    const int lane = t & 63;
    const int wv = t >> 6;      // 0..7
    const int m0 = blockIdx.x * GBM;
    const int n0 = blockIdx.y * GBN;

    // stage B once: wave wv stages cols wv*8 .. wv*8+7 (1KB each; lane l -> slot l)
#pragma unroll
    for (int it = 0; it < 8; ++it) {
        int c = wv * 8 + it;
        const unsigned short* src = Wt + (size_t)(n0 + c) * DIN + ((lane ^ (c & 7)) * 8);
        gload16(src, Bs + c * 1024);
    }

    // per-lane a-vector entries for the fused score dots
    float as_[4], ad_[4];
#pragma unroll
    for (int cf = 0; cf < 4; ++cf) {
        int col = n0 + cf * 16 + (lane & 15);
        as_[cf] = av[col];
        ad_[cf] = av[DOUT + col];
    }

    f32x4 acc[2][4] = {};
    const int g = lane >> 4;
    int row0 = m0 + wv * 32 + (lane & 15);
    int r0 = min(row0, M - 1);
    int r1 = min(row0 + 16, M - 1);
    const float* pA0 = x + (size_t)r0 * DIN + g * 8;
    const float* pA1 = x + (size_t)r1 * DIN + g * 8;

    __syncthreads();  // B resident; the only barrier

#pragma unroll 4
    for (int ks = 0; ks < DIN / 32; ++ks) {
        bf16x8 afr[2];
        {
            f32x4 v0 = *(const f32x4*)(pA0 + ks * 32);
            f32x4 v1 = *(const f32x4*)(pA0 + ks * 32 + 4);
            u32x4 p;
            p.x = cvtpk(v0.x, v0.y); p.y = cvtpk(v0.z, v0.w);
            p.z = cvtpk(v1.x, v1.y); p.w = cvtpk(v1.z, v1.w);
            afr[0] = *(bf16x8*)&p;
            f32x4 w0 = *(const f32x4*)(pA1 + ks * 32);
            f32x4 w1 = *(const f32x4*)(pA1 + ks * 32 + 4);
            u32x4 q;
            q.x = cvtpk(w0.x, w0.y); q.y = cvtpk(w0.z, w0.w);
            q.z = cvtpk(w1.x, w1.y); q.w = cvtpk(w1.z, w1.w);
            afr[1] = *(bf16x8*)&q;
        }
#pragma unroll
        for (int cf = 0; cf < 4; ++cf) {
            int col = cf * 16 + (lane & 15);
            bf16x8 bfr = *(const bf16x8*)(Bs + col * 1024 + (((ks * 4 + g) ^ (col & 7)) << 4));
            acc[0][cf] = __builtin_amdgcn_mfma_f32_16x16x32_bf16(afr[0], bfr, acc[0][cf], 0, 0, 0);
            acc[1][cf] = __builtin_amdgcn_mfma_f32_16x16x32_bf16(afr[1], bfr, acc[1][cf], 0, 0, 0);
        }
    }

    // epilogue: store hb + fused partial score dots (16-lane reduce + atomic per row)
#pragma unroll
    for (int rf = 0; rf < 2; ++rf) {
#pragma unroll
        for (int j = 0; j < 4; ++j) {
            int row = m0 + wv * 32 + rf * 16 + g * 4 + j;
            float ps = 0.f, pd = 0.f;
#pragma unroll
            for (int cf = 0; cf < 4; ++cf) {
                float v = acc[rf][cf][j];
                ps += v * as_[cf];
                pd += v * ad_[cf];
            }
#pragma unroll
            for (int off = 1; off < 16; off <<= 1) {
                ps += __shfl_xor(ps, off);
                pd += __shfl_xor(pd, off);
            }
            if (row < M) {
#pragma unroll
                for (int cf = 0; cf < 4; ++cf)
                    hb[(size_t)row * DOUT + n0 + cf * 16 + (lane & 15)] = f2bf(acc[rf][cf][j]);
                if ((lane & 15) == 0) {
                    atomicAdd(&s_src[row], ps);
                    atomicAdd(&s_dst[row], pd);
                }
            }
        }
    }
}

// ---------------- degree histogram ----------------
__global__ void hist_k(const int* __restrict__ src, int* __restrict__ deg, int E) {
    int i = blockIdx.x * blockDim.x + threadIdx.x;
    if (i < E) atomicAdd(&deg[src[i]], 1);
}

// ---------------- 3-stage scan: blocksum -> top scan -> block rescan ----------------
__global__ __launch_bounds__(256) void block_sum(const int* __restrict__ deg, int* __restrict__ bsum, int N) {
    __shared__ int wsum[4];
    int b = blockIdx.x, t = threadIdx.x;
    int idx = b * 1024 + t * 4;
    int s = 0;
    if (idx + 3 < N) {
        int4 v = *(const int4*)(deg + idx);
        s = v.x + v.y + v.z + v.w;
    } else {
        for (int i = 0; i < 4; i++) if (idx + i < N) s += deg[idx + i];
    }
#pragma unroll
    for (int off = 32; off > 0; off >>= 1) s += __shfl_xor(s, off);
    if ((t & 63) == 0) wsum[t >> 6] = s;
    __syncthreads();
    if (t == 0) bsum[b] = wsum[0] + wsum[1] + wsum[2] + wsum[3];
}

__global__ void scan_tops(const int* __restrict__ bsum, int* __restrict__ boff,
                          int* __restrict__ rowptr, int nb, int N, int E) {
    int t = threadIdx.x;  // single wave of 64
    int v = (t < nb) ? bsum[t] : 0;
    int x = v;
#pragma unroll
    for (int off = 1; off < 64; off <<= 1) {
        int y = __shfl_up(x, off);
        if (t >= off) x += y;
    }
    if (t < nb) boff[t] = x - v;
    if (t == 0) rowptr[N] = E;
}

__global__ __launch_bounds__(256) void scan_blk(const int* __restrict__ deg, const int* __restrict__ boff,
                                                int* __restrict__ rowptr, int* __restrict__ cursor, int N) {
    __shared__ int wsum[4];
    int b = blockIdx.x, t = threadIdx.x;
    int idx = b * 1024 + t * 4;
    int v0 = 0, v1 = 0, v2 = 0, v3 = 0;
    if (idx + 3 < N) {
        int4 v = *(const int4*)(deg + idx);
        v0 = v.x; v1 = v.y; v2 = v.z; v3 = v.w;
    } else if (idx < N) {
        v0 = deg[idx];
        if (idx + 1 < N) v1 = deg[idx + 1];
        if (idx + 2 < N) v2 = deg[idx + 2];
    }
    int s = v0 + v1 + v2 + v3;
    int lane = t & 63, wid = t >> 6;
    int x = s;
#pragma unroll
    for (int off = 1; off < 64; off <<= 1) {
        int y = __shfl_up(x, off);
        if (lane >= off) x += y;
    }
    if (lane == 63) wsum[wid] = x;
    __syncthreads();
    int add = boff[b];
    for (int ww = 0; ww < wid; ++ww) add += wsum[ww];
    int e0 = add + x - s;
    int e1 = e0 + v0, e2 = e1 + v1, e3 = e2 + v2;
    if (idx < N)     { rowptr[idx] = e0;     cursor[idx] = e0; }
    if (idx + 1 < N) { rowptr[idx + 1] = e1; cursor[idx + 1] = e1; }
    if (idx + 2 < N) { rowptr[idx + 2] = e2; cursor[idx + 2] = e2; }
    if (idx + 3 < N) { rowptr[idx + 3] = e3; cursor[idx + 3] = e3; }
}

// ---------------- edge scoring + CSR scatter (packed pair) ----------------
__global__ void edge_k(const int* __restrict__ src, const int* __restrict__ dst,
                       const float* __restrict__ s_src, const float* __restrict__ s_dst,
                       int* __restrict__ cursor, int2* __restrict__ csr, int E) {
    int i = blockIdx.x * blockDim.x + threadIdx.x;
    if (i >= E) return;
    int s = src[i], d = dst[i];
    float sc = s_src[s] + s_dst[d];
    float lrv = sc > 0.f ? sc : NEG_SLOPE * sc;
    float ev = __expf(-lrv);
    int pos = atomicAdd(&cursor[s], 1);
    csr[pos] = make_int2(d, __float_as_int(ev));
}

// ---------------- per-row gather SpMM (bf16 h) + div + ELU ----------------
__global__ __launch_bounds__(256) void gather_k(const unsigned short* __restrict__ hb,
                                                const int* __restrict__ rowptr,
                                                const int2* __restrict__ csr,
                                                float* __restrict__ out, int N) {
    int gt = blockIdx.x * blockDim.x + threadIdx.x;
    int w = gt >> 6;
    int lane = threadIdx.x & 63;
    if (w >= N) return;
    int s0 = rowptr[w], s1 = rowptr[w + 1];
    float a0 = 0.f, a1 = 0.f, a2 = 0.f, a3 = 0.f, rs = 0.f;
    for (int base = s0; base < s1; base += 64) {
        int cnt = min(64, s1 - base);
        int dv = 0; float ev = 0.f;
        if (lane < cnt) {
            int2 p = csr[base + lane];
            dv = p.x; ev = __int_as_float(p.y);
        }
        int jj = 0;
        for (; jj + 4 <= cnt; jj += 4) {
            int d0 = __shfl(dv, jj), d1 = __shfl(dv, jj + 1), d2 = __shfl(dv, jj + 2), d3 = __shfl(dv, jj + 3);
            float e0 = __shfl(ev, jj), e1 = __shfl(ev, jj + 1), e2 = __shfl(ev, jj + 2), e3 = __shfl(ev, jj + 3);
            ushort4 h0 = *(const ushort4*)(hb + (size_t)d0 * DOUT + lane * 4);
            ushort4 h1 = *(const ushort4*)(hb + (size_t)d1 * DOUT + lane * 4);
            ushort4 h2 = *(const ushort4*)(hb + (size_t)d2 * DOUT + lane * 4);
            ushort4 h3 = *(const ushort4*)(hb + (size_t)d3 * DOUT + lane * 4);
            a0 += e0 * bf2f(h0.x) + e1 * bf2f(h1.x) + e2 * bf2f(h2.x) + e3 * bf2f(h3.x);
            a1 += e0 * bf2f(h0.y) + e1 * bf2f(h1.y) + e2 * bf2f(h2.y) + e3 * bf2f(h3.y);
            a2 += e0 * bf2f(h0.z) + e1 * bf2f(h1.z) + e2 * bf2f(h2.z) + e3 * bf2f(h3.z);
            a3 += e0 * bf2f(h0.w) + e1 * bf2f(h1.w) + e2 * bf2f(h2.w) + e3 * bf2f(h3.w);
            rs += e0 + e1 + e2 + e3;
        }
        for (; jj < cnt; ++jj) {
            int d0 = __shfl(dv, jj);
            float e0 = __shfl(ev, jj);
            ushort4 h0 = *(const ushort4*)(hb + (size_t)d0 * DOUT + lane * 4);
            a0 += e0 * bf2f(h0.x);
            a1 += e0 * bf2f(h0.y);
            a2 += e0 * bf2f(h0.z);
            a3 += e0 * bf2f(h0.w);
            rs += e0;
        }
    }
    float inv = 1.f / rs;
    float4 v;
    v.x = a0 * inv; v.y = a1 * inv; v.z = a2 * inv; v.w = a3 * inv;
    v.x = v.x > 0.f ? v.x : __expf(v.x) - 1.f;
    v.y = v.y > 0.f ? v.y : __expf(v.y) - 1.f;
    v.z = v.z > 0.f ? v.z : __expf(v.z) - 1.f;
    v.w = v.w > 0.f ? v.w : __expf(v.w) - 1.f;
    *(float4*)(out + (size_t)w * DOUT + lane * 4) = v;
}

extern "C" void kernel_launch(void* const* d_in, const int* in_sizes, int n_in,
                              void* d_out, int out_size, void* d_ws, size_t ws_size,
                              hipStream_t stream) {
    const float* x = (const float*)d_in[0];
    const float* W = (const float*)d_in[1];
    const float* a = (const float*)d_in[2];
    const int* edge_src = (const int*)d_in[3];
    const int* edge_dst = (const int*)d_in[4];

    const int N = in_sizes[0] / DIN;
    const int E = in_sizes[3];
    const int nb = (N + 1023) / 1024;

    char* ws = (char*)d_ws;
    size_t off = 0;
    auto alloc = [&](size_t bytes) {
        void* p = ws + off;
        off += (bytes + 15) & ~(size_t)15;
        return p;
    };
    unsigned short* hb = (unsigned short*)alloc((size_t)N * DOUT * 2);
    unsigned short* Wt = (unsigned short*)alloc((size_t)DIN * DOUT * 2);
    int* rowptr = (int*)alloc((size_t)(N + 1) * 4);
    int* deg = (int*)alloc((size_t)N * 4);
    int* cursor = (int*)alloc((size_t)N * 4);
    float* s_src = (float*)alloc((size_t)N * 4);
    float* s_dst = (float*)alloc((size_t)N * 4);
    int2* csr = (int2*)alloc((size_t)E * 8);
    int* bsum = (int*)alloc((size_t)nb * 4);
    int* boff = (int*)alloc((size_t)nb * 4);
    (void)ws_size;

    float* out = (float*)d_out;

    prep<<<(DIN * DOUT + 255) / 256, 256, 0, stream>>>(W, Wt, deg, s_src, s_dst, N);
    hist_k<<<(E + 255) / 256, 256, 0, stream>>>(edge_src, deg, E);
    dim3 ggrid((N + GBM - 1) / GBM, DOUT / GBN);
    gemm_k<<<ggrid, 512, 0, stream>>>(x, Wt, hb, a, s_src, s_dst, N);
    block_sum<<<nb, 256, 0, stream>>>(deg, bsum, N);
    scan_tops<<<1, 64, 0, stream>>>(bsum, boff, rowptr, nb, N, E);
    scan_blk<<<nb, 256, 0, stream>>>(deg, boff, rowptr, cursor, N);
    edge_k<<<(E + 255) / 256, 256, 0, stream>>>(edge_src, edge_dst, s_src, s_dst,
                                                cursor, csr, E);
    gather_k<<<(N + 3) / 4, 256, 0, stream>>>(hb, rowptr, csr, out, N);
}

// Round 5
// 156.172 us; speedup vs baseline: 1.8686x; 1.1460x over previous
//
#include <hip/hip_runtime.h>
#include <math.h>

#define DIN 512
#define DOUT 256
#define NEG_SLOPE 0.01f

typedef __attribute__((ext_vector_type(8))) short bf16x8;
typedef __attribute__((ext_vector_type(4))) float f32x4;
typedef __attribute__((ext_vector_type(4))) unsigned int u32x4;

__device__ __forceinline__ unsigned short f2bf(float f) {
    unsigned int u = __float_as_uint(f);
    unsigned int r = (u + 0x7FFFu + ((u >> 16) & 1u)) >> 16;
    return (unsigned short)r;
}
__device__ __forceinline__ float bf2f(unsigned short u) {
    return __uint_as_float(((unsigned int)u) << 16);
}
__device__ __forceinline__ unsigned int cvtpk(float lo, float hi) {
    unsigned int r;
    asm("v_cvt_pk_bf16_f32 %0, %1, %2" : "=v"(r) : "v"(lo), "v"(hi));
    return r;
}
__device__ __forceinline__ void gload16(const void* g, void* l) {
    __builtin_amdgcn_global_load_lds(
        (const __attribute__((address_space(1))) void*)g,
        (__attribute__((address_space(3))) void*)l, 16, 0, 0);
}

// ---------------- prep: Wt = bf16(W^T)  [DOUT][DIN], zero deg/s_src/s_dst ------------
__global__ void prep(const float* __restrict__ W, unsigned short* __restrict__ Wt,
                     int* __restrict__ deg, float* __restrict__ s_src,
                     float* __restrict__ s_dst, int N) {
    int t = blockIdx.x * blockDim.x + threadIdx.x;
    if (t < DIN * DOUT) {
        int k = t & (DIN - 1);
        int c = t >> 9;
        Wt[t] = f2bf(W[(size_t)k * DOUT + c]);  // coalesced write, L2-cached strided read
    }
    if (t < N) { deg[t] = 0; s_src[t] = 0.f; s_dst[t] = 0.f; }
}

// ---------------- GEMM: hb = bf16( x @ W ), fused s_src/s_dst dots ----------
// Block = 128 rows x 256 cols (A read ONCE). 8 waves, each 32 rows x 128 cols.
// B staged in 4 K-chunks of 64KB LDS (single buffer, 2 blocks/CU overlap).
__global__ __launch_bounds__(512, 4) void gemm_k(const float* __restrict__ x,
                                                 const unsigned short* __restrict__ Wt,
                                                 unsigned short* __restrict__ hb,
                                                 const float* __restrict__ av,
                                                 float* __restrict__ s_src,
                                                 float* __restrict__ s_dst, int M) {
    __shared__ unsigned char Bs[65536];  // [col 0..255][swslot 0..15] x 16B
    const int t = threadIdx.x;
    const int lane = t & 63;
    const int l15 = lane & 15;
    const int g = lane >> 4;
    const int wv = t >> 6;      // 0..7
    const int wr = wv >> 1;     // 0..3 : row group (32 rows each)
    const int wc = wv & 1;      // 0..1 : col group (128 cols each)
    const int m0 = blockIdx.x * 128;

    f32x4 acc[2][8] = {};
    int row0 = m0 + wr * 32 + l15;
    int r0 = min(row0, M - 1);
    int r1 = min(row0 + 16, M - 1);
    const float* pA0 = x + (size_t)r0 * DIN + g * 8;
    const float* pA1 = x + (size_t)r1 * DIN + g * 8;

    for (int kc = 0; kc < 4; ++kc) {
        if (kc) __syncthreads();
        // stage B chunk kc: 4096 16B-slots, swizzled via pre-swizzled global source
#pragma unroll
        for (int it = 0; it < 8; ++it) {
            int fs = it * 512 + t;
            int col = fs >> 4;
            int slot = (fs & 15) ^ (col & 15);
            gload16(Wt + (size_t)col * DIN + kc * 128 + slot * 8, Bs + fs * 16);
        }
        __syncthreads();
#pragma unroll
        for (int ksl = 0; ksl < 4; ++ksl) {
            int ks = kc * 4 + ksl;
            bf16x8 afr0, afr1;
            {
                f32x4 v0 = *(const f32x4*)(pA0 + ks * 32);
                f32x4 v1 = *(const f32x4*)(pA0 + ks * 32 + 4);
                u32x4 p;
                p.x = cvtpk(v0.x, v0.y); p.y = cvtpk(v0.z, v0.w);
                p.z = cvtpk(v1.x, v1.y); p.w = cvtpk(v1.z, v1.w);
                afr0 = *(bf16x8*)&p;
                f32x4 w0 = *(const f32x4*)(pA1 + ks * 32);
                f32x4 w1 = *(const f32x4*)(pA1 + ks * 32 + 4);
                u32x4 q;
                q.x = cvtpk(w0.x, w0.y); q.y = cvtpk(w0.z, w0.w);
                q.z = cvtpk(w1.x, w1.y); q.w = cvtpk(w1.z, w1.w);
                afr1 = *(bf16x8*)&q;
            }
#pragma unroll
            for (int cf = 0; cf < 8; ++cf) {
                int col = wc * 128 + cf * 16 + l15;
                bf16x8 bfr = *(const bf16x8*)(Bs + col * 256 + (((ksl * 4 + g) ^ (col & 15)) << 4));
                acc[0][cf] = __builtin_amdgcn_mfma_f32_16x16x32_bf16(afr0, bfr, acc[0][cf], 0, 0, 0);
                acc[1][cf] = __builtin_amdgcn_mfma_f32_16x16x32_bf16(afr1, bfr, acc[1][cf], 0, 0, 0);
            }
        }
    }

    // epilogue: store hb + fused score dots (16-lane reduce + 1 atomic per row per wave)
    float as_[8], ad_[8];
#pragma unroll
    for (int cf = 0; cf < 8; ++cf) {
        int col = wc * 128 + cf * 16 + l15;
        as_[cf] = av[col];
        ad_[cf] = av[DOUT + col];
    }
#pragma unroll
    for (int rf = 0; rf < 2; ++rf) {
#pragma unroll
        for (int j = 0; j < 4; ++j) {
            int row = m0 + wr * 32 + rf * 16 + g * 4 + j;
            float ps = 0.f, pd = 0.f;
#pragma unroll
            for (int cf = 0; cf < 8; ++cf) {
                float v = acc[rf][cf][j];
                ps += v * as_[cf];
                pd += v * ad_[cf];
            }
#pragma unroll
            for (int off = 1; off < 16; off <<= 1) {
                ps += __shfl_xor(ps, off);
                pd += __shfl_xor(pd, off);
            }
            if (row < M) {
#pragma unroll
                for (int cf = 0; cf < 8; ++cf)
                    hb[(size_t)row * DOUT + wc * 128 + cf * 16 + l15] = f2bf(acc[rf][cf][j]);
                if (l15 == 0) {
                    atomicAdd(&s_src[row], ps);
                    atomicAdd(&s_dst[row], pd);
                }
            }
        }
    }
}

// ---------------- degree histogram ----------------
__global__ void hist_k(const int* __restrict__ src, int* __restrict__ deg, int E) {
    int i = blockIdx.x * blockDim.x + threadIdx.x;
    if (i < E) atomicAdd(&deg[src[i]], 1);
}

// ---------------- 3-stage scan: blocksum -> top scan -> block rescan ----------------
__global__ __launch_bounds__(256) void block_sum(const int* __restrict__ deg, int* __restrict__ bsum, int N) {
    __shared__ int wsum[4];
    int b = blockIdx.x, t = threadIdx.x;
    int idx = b * 1024 + t * 4;
    int s = 0;
    if (idx + 3 < N) {
        int4 v = *(const int4*)(deg + idx);
        s = v.x + v.y + v.z + v.w;
    } else {
        for (int i = 0; i < 4; i++) if (idx + i < N) s += deg[idx + i];
    }
#pragma unroll
    for (int off = 32; off > 0; off >>= 1) s += __shfl_xor(s, off);
    if ((t & 63) == 0) wsum[t >> 6] = s;
    __syncthreads();
    if (t == 0) bsum[b] = wsum[0] + wsum[1] + wsum[2] + wsum[3];
}

__global__ void scan_tops(const int* __restrict__ bsum, int* __restrict__ boff,
                          int* __restrict__ rowptr, int nb, int N, int E) {
    int t = threadIdx.x;  // single wave of 64
    int v = (t < nb) ? bsum[t] : 0;
    int x = v;
#pragma unroll
    for (int off = 1; off < 64; off <<= 1) {
        int y = __shfl_up(x, off);
        if (t >= off) x += y;
    }
    if (t < nb) boff[t] = x - v;
    if (t == 0) rowptr[N] = E;
}

__global__ __launch_bounds__(256) void scan_blk(const int* __restrict__ deg, const int* __restrict__ boff,
                                                int* __restrict__ rowptr, int* __restrict__ cursor, int N) {
    __shared__ int wsum[4];
    int b = blockIdx.x, t = threadIdx.x;
    int idx = b * 1024 + t * 4;
    int v0 = 0, v1 = 0, v2 = 0, v3 = 0;
    if (idx + 3 < N) {
        int4 v = *(const int4*)(deg + idx);
        v0 = v.x; v1 = v.y; v2 = v.z; v3 = v.w;
    } else if (idx < N) {
        v0 = deg[idx];
        if (idx + 1 < N) v1 = deg[idx + 1];
        if (idx + 2 < N) v2 = deg[idx + 2];
    }
    int s = v0 + v1 + v2 + v3;
    int lane = t & 63, wid = t >> 6;
    int x = s;
#pragma unroll
    for (int off = 1; off < 64; off <<= 1) {
        int y = __shfl_up(x, off);
        if (lane >= off) x += y;
    }
    if (lane == 63) wsum[wid] = x;
    __syncthreads();
    int add = boff[b];
    for (int ww = 0; ww < wid; ++ww) add += wsum[ww];
    int e0 = add + x - s;
    int e1 = e0 + v0, e2 = e1 + v1, e3 = e2 + v2;
    if (idx < N)     { rowptr[idx] = e0;     cursor[idx] = e0; }
    if (idx + 1 < N) { rowptr[idx + 1] = e1; cursor[idx + 1] = e1; }
    if (idx + 2 < N) { rowptr[idx + 2] = e2; cursor[idx + 2] = e2; }
    if (idx + 3 < N) { rowptr[idx + 3] = e3; cursor[idx + 3] = e3; }
}

// ---------------- edge scoring + CSR scatter (packed pair) ----------------
__global__ void edge_k(const int* __restrict__ src, const int* __restrict__ dst,
                       const float* __restrict__ s_src, const float* __restrict__ s_dst,
                       int* __restrict__ cursor, int2* __restrict__ csr, int E) {
    int i = blockIdx.x * blockDim.x + threadIdx.x;
    if (i >= E) return;
    int s = src[i], d = dst[i];
    float sc = s_src[s] + s_dst[d];
    float lrv = sc > 0.f ? sc : NEG_SLOPE * sc;
    float ev = __expf(-lrv);
    int pos = atomicAdd(&cursor[s], 1);
    csr[pos] = make_int2(d, __float_as_int(ev));
}

// ---------------- per-row gather SpMM (bf16 h) + div + ELU ----------------
__global__ __launch_bounds__(256) void gather_k(const unsigned short* __restrict__ hb,
                                                const int* __restrict__ rowptr,
                                                const int2* __restrict__ csr,
                                                float* __restrict__ out, int N) {
    int gt = blockIdx.x * blockDim.x + threadIdx.x;
    int w = gt >> 6;
    int lane = threadIdx.x & 63;
    if (w >= N) return;
    int s0 = rowptr[w], s1 = rowptr[w + 1];
    float a0 = 0.f, a1 = 0.f, a2 = 0.f, a3 = 0.f, rs = 0.f;
    for (int base = s0; base < s1; base += 64) {
        int cnt = min(64, s1 - base);
        int dv = 0; float ev = 0.f;
        if (lane < cnt) {
            int2 p = csr[base + lane];
            dv = p.x; ev = __int_as_float(p.y);
        }
        int jj = 0;
        for (; jj + 4 <= cnt; jj += 4) {
            int d0 = __shfl(dv, jj), d1 = __shfl(dv, jj + 1), d2 = __shfl(dv, jj + 2), d3 = __shfl(dv, jj + 3);
            float e0 = __shfl(ev, jj), e1 = __shfl(ev, jj + 1), e2 = __shfl(ev, jj + 2), e3 = __shfl(ev, jj + 3);
            ushort4 h0 = *(const ushort4*)(hb + (size_t)d0 * DOUT + lane * 4);
            ushort4 h1 = *(const ushort4*)(hb + (size_t)d1 * DOUT + lane * 4);
            ushort4 h2 = *(const ushort4*)(hb + (size_t)d2 * DOUT + lane * 4);
            ushort4 h3 = *(const ushort4*)(hb + (size_t)d3 * DOUT + lane * 4);
            a0 += e0 * bf2f(h0.x) + e1 * bf2f(h1.x) + e2 * bf2f(h2.x) + e3 * bf2f(h3.x);
            a1 += e0 * bf2f(h0.y) + e1 * bf2f(h1.y) + e2 * bf2f(h2.y) + e3 * bf2f(h3.y);
            a2 += e0 * bf2f(h0.z) + e1 * bf2f(h1.z) + e2 * bf2f(h2.z) + e3 * bf2f(h3.z);
            a3 += e0 * bf2f(h0.w) + e1 * bf2f(h1.w) + e2 * bf2f(h2.w) + e3 * bf2f(h3.w);
            rs += e0 + e1 + e2 + e3;
        }
        for (; jj < cnt; ++jj) {
            int d0 = __shfl(dv, jj);
            float e0 = __shfl(ev, jj);
            ushort4 h0 = *(const ushort4*)(hb + (size_t)d0 * DOUT + lane * 4);
            a0 += e0 * bf2f(h0.x);
            a1 += e0 * bf2f(h0.y);
            a2 += e0 * bf2f(h0.z);
            a3 += e0 * bf2f(h0.w);
            rs += e0;
        }
    }
    float inv = 1.f / rs;
    float4 v;
    v.x = a0 * inv; v.y = a1 * inv; v.z = a2 * inv; v.w = a3 * inv;
    v.x = v.x > 0.f ? v.x : __expf(v.x) - 1.f;
    v.y = v.y > 0.f ? v.y : __expf(v.y) - 1.f;
    v.z = v.z > 0.f ? v.z : __expf(v.z) - 1.f;
    v.w = v.w > 0.f ? v.w : __expf(v.w) - 1.f;
    *(float4*)(out + (size_t)w * DOUT + lane * 4) = v;
}

extern "C" void kernel_launch(void* const* d_in, const int* in_sizes, int n_in,
                              void* d_out, int out_size, void* d_ws, size_t ws_size,
                              hipStream_t stream) {
    const float* x = (const float*)d_in[0];
    const float* W = (const float*)d_in[1];
    const float* a = (const float*)d_in[2];
    const int* edge_src = (const int*)d_in[3];
    const int* edge_dst = (const int*)d_in[4];

    const int N = in_sizes[0] / DIN;
    const int E = in_sizes[3];
    const int nb = (N + 1023) / 1024;

    char* ws = (char*)d_ws;
    size_t off = 0;
    auto alloc = [&](size_t bytes) {
        void* p = ws + off;
        off += (bytes + 15) & ~(size_t)15;
        return p;
    };
    unsigned short* hb = (unsigned short*)alloc((size_t)N * DOUT * 2);
    unsigned short* Wt = (unsigned short*)alloc((size_t)DIN * DOUT * 2);
    int* rowptr = (int*)alloc((size_t)(N + 1) * 4);
    int* deg = (int*)alloc((size_t)N * 4);
    int* cursor = (int*)alloc((size_t)N * 4);
    float* s_src = (float*)alloc((size_t)N * 4);
    float* s_dst = (float*)alloc((size_t)N * 4);
    int2* csr = (int2*)alloc((size_t)E * 8);
    int* bsum = (int*)alloc((size_t)nb * 4);
    int* boff = (int*)alloc((size_t)nb * 4);
    (void)ws_size;

    float* out = (float*)d_out;

    prep<<<(DIN * DOUT + 255) / 256, 256, 0, stream>>>(W, Wt, deg, s_src, s_dst, N);
    hist_k<<<(E + 255) / 256, 256, 0, stream>>>(edge_src, deg, E);
    gemm_k<<<(N + 127) / 128, 512, 0, stream>>>(x, Wt, hb, a, s_src, s_dst, N);
    block_sum<<<nb, 256, 0, stream>>>(deg, bsum, N);
    scan_tops<<<1, 64, 0, stream>>>(bsum, boff, rowptr, nb, N, E);
    scan_blk<<<nb, 256, 0, stream>>>(deg, boff, rowptr, cursor, N);
    edge_k<<<(E + 255) / 256, 256, 0, stream>>>(edge_src, edge_dst, s_src, s_dst,
                                                cursor, csr, E);
    gather_k<<<(N + 3) / 4, 256, 0, stream>>>(hb, rowptr, csr, out, N);
}